// Round 2
// baseline (262.773 us; speedup 1.0000x reference)
//
#include <hip/hip_runtime.h>
#include <hip/hip_bf16.h>
#include <cstdint>
#include <cstddef>

typedef __bf16 bf16_t;
typedef __bf16 bf16x4 __attribute__((ext_vector_type(4)));
typedef __bf16 bf16x8 __attribute__((ext_vector_type(8)));
typedef float  f32x4  __attribute__((ext_vector_type(4)));

#define NB   16
#define NC   256
#define NO   256
#define SD   512
#define NPIX 4096   // 64*64
#define CPAD 36     // LDS channel pad: breaks pow2 banks, keeps 8B alignment

// workspace layout (bytes)
#define WS_S   0        // s   [16][256] f32  (16 KB)
#define WS_D   16384    // d   [16][256] f32  (16 KB)
#define WS_WSQ 32768    // wsq [256][256] f32 (256 KB)
#define WS_WT  294912   // wT  [9][256][256] bf16 (1.125 MB)

// ---------------------------------------------------------------------------
// prep1: blocks 0..15  -> s[b,i]   = style[b,:] . mod_w[i,:] + mod_b[i]
//        blocks 16..271-> wsq[o,i] = sum_t w[o,i,t]^2 ; wT[t][o][i] = bf16(w[o][i][t])
// All inputs are FLOAT32 (reference dtypes).
// ---------------------------------------------------------------------------
__global__ __launch_bounds__(256) void prep1(
    const float* __restrict__ style, const float* __restrict__ weight,
    const float* __restrict__ mod_w, const float* __restrict__ mod_b,
    float* __restrict__ s_buf, float* __restrict__ wsq, bf16_t* __restrict__ wT)
{
    const int blk = blockIdx.x;
    const int tid = threadIdx.x;
    if (blk < 16) {
        const int b = blk, i = tid;
        const float* st = style + b * SD;
        const float* mw = mod_w + i * SD;
        float acc = 0.f;
        for (int k = 0; k < SD; k += 4) {
            float4 a = *(const float4*)(st + k);
            float4 c = *(const float4*)(mw + k);
            acc += a.x * c.x + a.y * c.y + a.z * c.z + a.w * c.w;
        }
        s_buf[b * NC + i] = acc + mod_b[i];
    } else {
        const int o = blk - 16, i = tid;
        const float* wp = weight + (o * NC + i) * 9;
        float q = 0.f;
        #pragma unroll
        for (int t = 0; t < 9; ++t) {
            float v = wp[t];
            q += v * v;
            wT[t * (NO * NC) + o * NC + i] = (bf16_t)v;
        }
        wsq[o * NC + i] = q;
    }
}

// ---------------------------------------------------------------------------
// prep2: d[b,o] = rsqrt( sum_i wsq[o,i] * s[b,i]^2 + eps )
// ---------------------------------------------------------------------------
__global__ __launch_bounds__(256) void prep2(
    const float* __restrict__ s_buf, const float* __restrict__ wsq,
    float* __restrict__ d_buf)
{
    const int b = blockIdx.x, o = threadIdx.x;
    const float* wq = wsq + o * NC;
    const float* sb = s_buf + b * NC;
    float sum = 0.f;
    for (int i = 0; i < NC; ++i) {
        float sv = sb[i];
        sum += wq[i] * sv * sv;
    }
    d_buf[b * NC + o] = rsqrtf(sum + 1e-8f);
}

// ---------------------------------------------------------------------------
// conv: implicit-GEMM, per batch:  C[o,p] = sum_{tap,ic} wT[tap][o][ic] * xs[...]
// block: 128 out_ch x 128 positions (2 image rows); 4 waves, each 64x64 via
// 4x4 frags of mfma_f32_16x16x32_bf16. K-loop: 8 channel chunks x 9 taps.
// A (weights, bf16) staged via global_load_lds width=16, double-buffered per tap.
// B (x*s) staged fp32->bf16 through VGPRs, channel-innermost LDS layout.
// ---------------------------------------------------------------------------
__device__ __forceinline__ void stage_a(const bf16_t* __restrict__ wT_tap,
                                        int o0, int ic0, bf16_t* dst, int tid)
{
    #pragma unroll
    for (int it = 0; it < 2; ++it) {
        int s = it * 256 + tid;                       // 512 16B segments
        const bf16_t* g = wT_tap + (o0 + (s >> 2)) * NC + ic0 + (s & 3) * 8;
        __builtin_amdgcn_global_load_lds(
            (const __attribute__((address_space(1))) void*)g,
            (__attribute__((address_space(3))) void*)(dst + s * 8),
            16, 0, 0);
    }
}

__global__ __launch_bounds__(256) void conv_mfma(
    const float* __restrict__ x,
    const bf16_t* __restrict__ wT,
    const float* __restrict__ s_buf,
    const float* __restrict__ d_buf,
    float* __restrict__ out)
{
    __shared__ bf16_t lds_a[2][128 * 32];       // 2 x 8 KB, A double buffer
    __shared__ bf16_t lds_b[4 * 64 * CPAD];     // 18 KB, x rows (transposed, scaled)

    const int tid   = threadIdx.x;
    const int lane  = tid & 63;
    const int wv    = tid >> 6;
    const int wo    = wv >> 1;       // wave o-half
    const int wp    = wv & 1;        // wave p-half (= image row within tile)
    const int pt    = blockIdx.x;    // 0..31 position tiles (2 rows each)
    const int o0    = blockIdx.y * 128;
    const int batch = blockIdx.z;
    const int row0  = pt * 2;

    const int l15 = lane & 15;
    const int k0  = (lane >> 4) * 8;

    const int colB = tid & 63;       // staging: column
    const int cgrp = tid >> 6;       // staging: channel group (8 ch each)

    f32x4 acc[4][4];
    #pragma unroll
    for (int i = 0; i < 4; ++i)
        #pragma unroll
        for (int j = 0; j < 4; ++j) {
            f32x4 z = {0.f, 0.f, 0.f, 0.f};
            acc[i][j] = z;
        }

    bf16x8 bzero;
    #pragma unroll
    for (int j = 0; j < 8; ++j) bzero[j] = (bf16_t)0.f;

    for (int chunk = 0; chunk < 8; ++chunk) {
        const int ic0 = chunk * 32;

        // ---- stage B: lds_b[(r*64+col)*CPAD + ch] = bf16(x[b][ic0+ch][row0-1+r][col]*s) ----
        {
            float sv[8];
            #pragma unroll
            for (int c = 0; c < 8; ++c)
                sv[c] = s_buf[batch * NC + ic0 + cgrp * 8 + c];
            const float* xbase = x + (size_t)(batch * NC + ic0 + cgrp * 8) * NPIX + colB;
            #pragma unroll
            for (int r = 0; r < 4; ++r) {
                const int gy = row0 - 1 + r;
                const bool valid = ((unsigned)gy < 64u);
                const int lbase = (r * 64 + colB) * CPAD + cgrp * 8;
                #pragma unroll
                for (int cp = 0; cp < 4; ++cp) {
                    float v0 = 0.f, v1 = 0.f;
                    if (valid) {
                        v0 = xbase[(2 * cp)     * NPIX + gy * 64] * sv[2 * cp];
                        v1 = xbase[(2 * cp + 1) * NPIX + gy * 64] * sv[2 * cp + 1];
                    }
                    union { bf16_t h[2]; uint32_t u; } pk;
                    pk.h[0] = (bf16_t)v0;
                    pk.h[1] = (bf16_t)v1;
                    *(uint32_t*)&lds_b[lbase + 2 * cp] = pk.u;  // 4B aligned
                }
            }
        }
        stage_a(wT, o0, ic0, &lds_a[0][0], tid);   // tap 0 into buf 0
        __syncthreads();

        #pragma unroll
        for (int tap = 0; tap < 9; ++tap) {
            if (tap < 8)
                stage_a(wT + (tap + 1) * (NO * NC), o0, ic0,
                        &lds_a[(tap + 1) & 1][0], tid);

            const bf16_t* abuf = &lds_a[tap & 1][0];
            const int kh = tap / 3, kw = tap % 3;

            bf16x8 af[4];
            #pragma unroll
            for (int of = 0; of < 4; ++of)
                af[of] = *(const bf16x8*)&abuf[(wo * 64 + of * 16 + l15) * 32 + k0];

            const int r = wp + kh;   // lds row for this wave's output row + tap dy
            bf16x8 bfr[4];
            #pragma unroll
            for (int nf = 0; nf < 4; ++nf) {
                const int c = nf * 16 + l15 + kw - 1;
                if ((unsigned)c < 64u) {
                    const bf16_t* p = &lds_b[(r * 64 + c) * CPAD + k0];
                    bf16x4 lo = *(const bf16x4*)p;        // 8B aligned
                    bf16x4 hi = *(const bf16x4*)(p + 4);
                    bfr[nf] = __builtin_shufflevector(lo, hi, 0, 1, 2, 3, 4, 5, 6, 7);
                } else {
                    bfr[nf] = bzero;                       // horizontal zero-pad
                }
            }

            #pragma unroll
            for (int of = 0; of < 4; ++of)
                #pragma unroll
                for (int nf = 0; nf < 4; ++nf)
                    acc[of][nf] = __builtin_amdgcn_mfma_f32_16x16x32_bf16(
                        af[of], bfr[nf], acc[of][nf], 0, 0, 0);

            __syncthreads();
        }
    }

    // ---- epilogue: y = acc * d[b,o], store fp32 ----
    const int p_base = pt * 128 + wp * 64;
    #pragma unroll
    for (int of = 0; of < 4; ++of) {
        #pragma unroll
        for (int rg = 0; rg < 4; ++rg) {
            const int o_g = o0 + wo * 64 + of * 16 + (lane >> 4) * 4 + rg;
            const float dv = d_buf[batch * NO + o_g];
            const size_t obase = (size_t)(batch * NO + o_g) * NPIX;
            #pragma unroll
            for (int nf = 0; nf < 4; ++nf) {
                const int p_g = p_base + nf * 16 + l15;
                out[obase + p_g] = acc[of][nf][rg] * dv;
            }
        }
    }
}

// ---------------------------------------------------------------------------
extern "C" void kernel_launch(void* const* d_in, const int* in_sizes, int n_in,
                              void* d_out, int out_size, void* d_ws, size_t ws_size,
                              hipStream_t stream)
{
    const float* x      = (const float*)d_in[0];
    const float* style  = (const float*)d_in[1];
    const float* weight = (const float*)d_in[2];
    const float* mod_w  = (const float*)d_in[3];
    const float* mod_b  = (const float*)d_in[4];
    float* out = (float*)d_out;

    char* ws = (char*)d_ws;
    float*  s_buf = (float*)(ws + WS_S);
    float*  d_buf = (float*)(ws + WS_D);
    float*  wsq   = (float*)(ws + WS_WSQ);
    bf16_t* wT    = (bf16_t*)(ws + WS_WT);

    hipLaunchKernelGGL(prep1, dim3(272), dim3(256), 0, stream,
                       style, weight, mod_w, mod_b, s_buf, wsq, wT);
    hipLaunchKernelGGL(prep2, dim3(16), dim3(256), 0, stream, s_buf, wsq, d_buf);
    hipLaunchKernelGGL(conv_mfma, dim3(32, 2, 16), dim3(256), 0, stream,
                       x, wT, s_buf, d_buf, out);
}